// Round 2
// baseline (671.314 us; speedup 1.0000x reference)
//
#include <hip/hip_runtime.h>
#include <hip/hip_bf16.h>

typedef unsigned short u16;
typedef unsigned int u32;
typedef __attribute__((ext_vector_type(8))) short short8;   // 8 x bf16 (4 VGPRs)
typedef __attribute__((ext_vector_type(4))) float f32x4;

#define L_TOK 8192
#define BATCH 4
#define DIM 1024
#define KSEL 6144
#define NTOK (BATCH * L_TOK)   // 32768

// ---------- helpers ----------
__device__ __forceinline__ u16 f2bf(float f) {  // RNE fp32 -> bf16
    u32 u = __float_as_uint(f);
    return (u16)((u + 0x7fffu + ((u >> 16) & 1u)) >> 16);
}
__device__ __forceinline__ u32 cvt2(float a, float b) {  // pack 2 bf16 (RNE)
    __hip_bfloat162 h = __float22bfloat162_rn(float2{a, b});
    u32 r;
    __builtin_memcpy(&r, &h, 4);
    return r;
}
__device__ __forceinline__ float gelu_tanh(float v) {
    float inner = 0.7978845608028654f * (v + 0.044715f * v * v * v);
    return 0.5f * v * (1.0f + tanhf(inner));
}
__device__ __forceinline__ void async_copy16(const void* g, void* l) {
    __builtin_amdgcn_global_load_lds(
        (const __attribute__((address_space(1))) void*)g,
        (__attribute__((address_space(3))) void*)l, 16, 0, 0);
}

// ---------- 1) router scores: scores[t] = sum_d x[t][d] * w_router[d] (fp64 acc) ----------
__global__ __launch_bounds__(256) void score_kernel(const float* __restrict__ x,
                                                    const float* __restrict__ wr,
                                                    float* __restrict__ scores) {
    int token = blockIdx.x * 4 + (threadIdx.x >> 6);
    int lane = threadIdx.x & 63;
    const float4* xr = (const float4*)(x + (size_t)token * DIM) + lane * 4;
    const float4* wp = (const float4*)wr + lane * 4;
    double acc = 0.0;
#pragma unroll
    for (int c = 0; c < 4; ++c) {
        float4 xv = xr[c];
        float4 wv = wp[c];
        acc += (double)xv.x * wv.x + (double)xv.y * wv.y +
               (double)xv.z * wv.z + (double)xv.w * wv.w;
    }
#pragma unroll
    for (int off = 32; off > 0; off >>= 1) acc += __shfl_down(acc, off, 64);
    if (lane == 0) scores[token] = (float)acc;
}

// ---------- 2) per-row top-k set selection via radix-value binary search ----------
__global__ __launch_bounds__(1024) void select_kernel(const float* __restrict__ scores,
                                                      int* __restrict__ mask) {
    __shared__ u32 keys[L_TOK];      // 32 KB
    __shared__ int red[17];
    const int b = blockIdx.x;
    const int tid = threadIdx.x;
    const float* s = scores + (size_t)b * L_TOK;
    for (int i = tid; i < L_TOK; i += 1024) {
        u32 u = __float_as_uint(s[i]);
        keys[i] = (u & 0x80000000u) ? ~u : (u | 0x80000000u);  // order-preserving map
    }
    __syncthreads();

    u32 lo = 0u, hi = 0xFFFFFFFFu;
    while (lo < hi) {
        unsigned long long span = (unsigned long long)hi - lo + 1ull;
        u32 mid = lo + (u32)(span >> 1);   // > lo always
        int my = 0;
        for (int i = tid; i < L_TOK; i += 1024) my += (keys[i] >= mid);
#pragma unroll
        for (int off = 32; off > 0; off >>= 1) my += __shfl_down(my, off, 64);
        __syncthreads();
        if ((tid & 63) == 0) red[tid >> 6] = my;
        __syncthreads();
        if (tid == 0) {
            int tot = 0;
            for (int w = 0; w < 16; ++w) tot += red[w];
            red[16] = tot;
        }
        __syncthreads();
        int cnt = red[16];
        if (cnt >= KSEL) lo = mid; else hi = mid - 1;
    }
    const u32 T = lo;   // k-th largest key value (uniform across threads)

    int myg = 0;
    for (int i = tid; i < L_TOK; i += 1024) myg += (keys[i] > T);
#pragma unroll
    for (int off = 32; off > 0; off >>= 1) myg += __shfl_down(myg, off, 64);
    __syncthreads();
    if ((tid & 63) == 0) red[tid >> 6] = myg;
    __syncthreads();
    if (tid == 0) {
        int tot = 0;
        for (int w = 0; w < 16; ++w) tot += red[w];
        red[16] = tot;
    }
    __syncthreads();
    const int need_eq = KSEL - red[16];   // ==T tokens to take (lowest index first)

    for (int i = tid; i < L_TOK; i += 1024) {
        u32 key = keys[i];
        int sel = 0;
        if (key > T) sel = 1;
        else if (key == T) {
            int rank = 0;
            for (int j = 0; j < i; ++j) rank += (keys[j] == T);  // ties are rare
            sel = (rank < need_eq) ? 1 : 0;
        }
        mask[(size_t)b * L_TOK + i] = sel;
    }
}

// ---------- 3) convert+transpose w_block (fp32) -> WT bf16 [n][k] ----------
__global__ __launch_bounds__(256) void transpose_kernel(const float* __restrict__ W,
                                                        u16* __restrict__ WT) {
    __shared__ u16 tile[32][33];
    int bx = blockIdx.x * 32, by = blockIdx.y * 32;
    int tx = threadIdx.x & 31, ty = threadIdx.x >> 5;  // 32 x 8
    for (int r = ty; r < 32; r += 8)
        tile[r][tx] = f2bf(W[(size_t)(by + r) * DIM + bx + tx]);
    __syncthreads();
    for (int r = ty; r < 32; r += 8)
        WT[(size_t)(bx + r) * DIM + by + tx] = tile[tx][r];
}

// ---------- 4) GEMM y = x @ W (bf16 MFMA, fp32 acc), gelu, masked scatter ----------
#define BM 128
#define BN 128
#define BK 32

__global__ __launch_bounds__(256) void gemm_kernel(const float* __restrict__ X,
                                                   const u16* __restrict__ WT,
                                                   const int* __restrict__ mask,
                                                   float* __restrict__ out) {
    __shared__ alignas(16) u16 As[BM * BK];  // [row][k] bf16 (converted in regs)
    __shared__ alignas(16) u16 Bs[BN * BK];  // [n][k]   bf16 (async from WT)
    const int tid = threadIdx.x;
    const int wave = tid >> 6, lane = tid & 63;
    const int wm = wave >> 1, wn = wave & 1;
    const size_t rowbase = (size_t)blockIdx.x * BM;
    const int colbase = blockIdx.y * BN;

    f32x4 acc[4][4] = {};

    // B staging: 512 x 16B chunks via global_load_lds
    const int cb0 = tid, cb1 = tid + 256;
    const int br0 = cb0 >> 2, bk0 = (cb0 & 3) * 8;
    const int br1 = cb1 >> 2, bk1 = (cb1 & 3) * 8;
    // A staging: thread t handles 16 contiguous fp32 of row (t>>1), half (t&1)
    const int arow = tid >> 1, ahalf = tid & 1;

    const int q = lane >> 4, mrow = lane & 15;

    for (int kt = 0; kt < DIM; kt += BK) {
        async_copy16(WT + (size_t)(colbase + br0) * DIM + kt + bk0, Bs + cb0 * 8);
        async_copy16(WT + (size_t)(colbase + br1) * DIM + kt + bk1, Bs + cb1 * 8);

        const float4* xp = (const float4*)(X + (rowbase + arow) * DIM + kt + ahalf * 16);
        float4 v0 = xp[0], v1 = xp[1], v2 = xp[2], v3 = xp[3];
        union { short8 s[2]; u32 u[8]; } pk;
        pk.u[0] = cvt2(v0.x, v0.y); pk.u[1] = cvt2(v0.z, v0.w);
        pk.u[2] = cvt2(v1.x, v1.y); pk.u[3] = cvt2(v1.z, v1.w);
        pk.u[4] = cvt2(v2.x, v2.y); pk.u[5] = cvt2(v2.z, v2.w);
        pk.u[6] = cvt2(v3.x, v3.y); pk.u[7] = cvt2(v3.z, v3.w);
        *(short8*)(As + arow * BK + ahalf * 16)     = pk.s[0];
        *(short8*)(As + arow * BK + ahalf * 16 + 8) = pk.s[1];

        __syncthreads();   // drains vmcnt (B) + lgkm (A writes)

        short8 a[4], b[4];
#pragma unroll
        for (int i = 0; i < 4; ++i)
            a[i] = *(const short8*)(As + (wm * 64 + i * 16 + mrow) * BK + q * 8);
#pragma unroll
        for (int j = 0; j < 4; ++j)
            b[j] = *(const short8*)(Bs + (wn * 64 + j * 16 + mrow) * BK + q * 8);
#pragma unroll
        for (int i = 0; i < 4; ++i)
#pragma unroll
            for (int j = 0; j < 4; ++j)
                acc[i][j] = __builtin_amdgcn_mfma_f32_16x16x32_bf16(a[i], b[j], acc[i][j], 0, 0, 0);
        __syncthreads();   // all ds_reads done before next staging overwrite
    }

    // epilogue: C/D layout col=lane&15, row=(lane>>4)*4+reg
#pragma unroll
    for (int i = 0; i < 4; ++i) {
#pragma unroll
        for (int r = 0; r < 4; ++r) {
            size_t grow = rowbase + wm * 64 + i * 16 + q * 4 + r;
            if (mask[grow]) {
#pragma unroll
                for (int j = 0; j < 4; ++j) {
                    float g = gelu_tanh(acc[i][j][r]);
                    int col = colbase + wn * 64 + j * 16 + mrow;
                    out[grow * DIM + col] = g;
                }
            }
        }
    }
}

// ---------- 5) pass-through for unselected tokens (bit-exact fp32 copy) ----------
__global__ __launch_bounds__(256) void passthrough_kernel(const float* __restrict__ x,
                                                          const int* __restrict__ mask,
                                                          float* __restrict__ out) {
    size_t c = (size_t)blockIdx.x * 256 + threadIdx.x;  // float4 chunk id
    int token = (int)(c >> 8);                          // 256 chunks per token
    if (!mask[token]) {
        ((float4*)out)[c] = ((const float4*)x)[c];
    }
}

extern "C" void kernel_launch(void* const* d_in, const int* in_sizes, int n_in,
                              void* d_out, int out_size, void* d_ws, size_t ws_size,
                              hipStream_t stream) {
    const float* x  = (const float*)d_in[0];   // [4,8192,1024] fp32
    const float* wr = (const float*)d_in[1];   // [1024] fp32
    const float* wb = (const float*)d_in[2];   // [1024,1024] fp32
    float* out = (float*)d_out;

    float* scores = (float*)d_ws;                            // 128 KB
    int*   mask   = (int*)((char*)d_ws + NTOK * 4);          // 128 KB
    u16*   WT     = (u16*)((char*)d_ws + NTOK * 8);          // 2 MB bf16

    score_kernel<<<NTOK / 4, 256, 0, stream>>>(x, wr, scores);
    select_kernel<<<BATCH, 1024, 0, stream>>>(scores, mask);
    transpose_kernel<<<dim3(DIM / 32, DIM / 32), 256, 0, stream>>>(wb, WT);
    gemm_kernel<<<dim3(NTOK / BM, DIM / BN), 256, 0, stream>>>(x, WT, mask, out);
    passthrough_kernel<<<(NTOK * 256) / 256, 256, 0, stream>>>(x, mask, out);
}

// Round 3
// 657.331 us; speedup vs baseline: 1.0213x; 1.0213x over previous
//
#include <hip/hip_runtime.h>
#include <hip/hip_bf16.h>

typedef unsigned short u16;
typedef unsigned int u32;
typedef __attribute__((ext_vector_type(8))) short short8;   // 8 x bf16 (4 VGPRs)
typedef __attribute__((ext_vector_type(4))) float f32x4;

#define L_TOK 8192
#define BATCH 4
#define DIM 1024
#define KSEL 6144
#define NTOK (BATCH * L_TOK)   // 32768

// ---------- helpers ----------
__device__ __forceinline__ u16 f2bf(float f) {  // RNE fp32 -> bf16
    u32 u = __float_as_uint(f);
    return (u16)((u + 0x7fffu + ((u >> 16) & 1u)) >> 16);
}
__device__ __forceinline__ u32 cvt2(float a, float b) {  // pack 2 bf16 (RNE)
    __hip_bfloat162 h = __float22bfloat162_rn(float2{a, b});
    u32 r;
    __builtin_memcpy(&r, &h, 4);
    return r;
}
__device__ __forceinline__ float gelu_tanh(float v) {
    float inner = 0.7978845608028654f * (v + 0.044715f * v * v * v);
    return 0.5f * v * (1.0f + tanhf(inner));
}
__device__ __forceinline__ void async_copy16(const void* g, void* l) {
    __builtin_amdgcn_global_load_lds(
        (const __attribute__((address_space(1))) void*)g,
        (__attribute__((address_space(3))) void*)l, 16, 0, 0);
}

// ---------- 1) router scores: scores[t] = sum_d x[t][d] * w_router[d] (fp64 acc) ----------
__global__ __launch_bounds__(256) void score_kernel(const float* __restrict__ x,
                                                    const float* __restrict__ wr,
                                                    float* __restrict__ scores) {
    int token = blockIdx.x * 4 + (threadIdx.x >> 6);
    int lane = threadIdx.x & 63;
    const float4* xr = (const float4*)(x + (size_t)token * DIM) + lane * 4;
    const float4* wp = (const float4*)wr + lane * 4;
    double acc = 0.0;
#pragma unroll
    for (int c = 0; c < 4; ++c) {
        float4 xv = xr[c];
        float4 wv = wp[c];
        acc += (double)xv.x * wv.x + (double)xv.y * wv.y +
               (double)xv.z * wv.z + (double)xv.w * wv.w;
    }
#pragma unroll
    for (int off = 32; off > 0; off >>= 1) acc += __shfl_down(acc, off, 64);
    if (lane == 0) scores[token] = (float)acc;
}

// ---------- 2) per-row top-k via 4-pass MSB-first radix select ----------
__global__ __launch_bounds__(1024) void select_kernel(const float* __restrict__ scores,
                                                      int* __restrict__ mask) {
    __shared__ u32 keys[L_TOK];      // 32 KB
    __shared__ int hist[256];
    __shared__ int g0[256], g1[256];
    __shared__ int sel_digit, greater_cnt;
    const int b = blockIdx.x;
    const int tid = threadIdx.x;
    const float* s = scores + (size_t)b * L_TOK;
    for (int i = tid; i < L_TOK; i += 1024) {
        u32 u = __float_as_uint(s[i]);
        keys[i] = (u & 0x80000000u) ? ~u : (u | 0x80000000u);  // order-preserving map
    }

    u32 prefix = 0;
    int need = KSEL;
#pragma unroll
    for (int pass = 0; pass < 4; ++pass) {
        const int shift = 24 - 8 * pass;
        const u32 pmask = (pass == 0) ? 0u : (0xFFFFFFFFu << (shift + 8));
        if (tid < 256) hist[tid] = 0;
        __syncthreads();   // hist zeroed; also covers initial keys[] visibility
        for (int i = tid; i < L_TOK; i += 1024) {
            u32 key = keys[i];
            if ((key & pmask) == prefix)
                atomicAdd(&hist[(key >> shift) & 0xffu], 1);
        }
        __syncthreads();
        // suffix-inclusive scan: G[d] = #active with digit >= d (Hillis-Steele)
        if (tid < 256) g0[tid] = hist[tid];
        __syncthreads();
        int* src = g0;
        int* dst = g1;
        for (int step = 1; step < 256; step <<= 1) {
            if (tid < 256) {
                int v = src[tid];
                if (tid + step < 256) v += src[tid + step];
                dst[tid] = v;
            }
            __syncthreads();
            int* t = src; src = dst; dst = t;
        }
        // pick d* = max{d : G[d] >= need}; count of digits > d* = G[d*+1]
        if (tid < 256) {
            int Gd = src[tid];
            int Gn = (tid == 255) ? 0 : src[tid + 1];
            if (Gd >= need && Gn < need) { sel_digit = tid; greater_cnt = Gn; }
        }
        __syncthreads();
        prefix |= ((u32)sel_digit) << shift;
        need -= greater_cnt;
        __syncthreads();
    }
    const u32 T = prefix;        // exact k-th largest key
    const int need_eq = need;    // how many ==T tokens to take (lowest index first)

    for (int i = tid; i < L_TOK; i += 1024) {
        u32 key = keys[i];
        int sel = 0;
        if (key > T) sel = 1;
        else if (key == T) {
            int rank = 0;
            for (int j = 0; j < i; ++j) rank += (keys[j] == T);  // ties are rare
            sel = (rank < need_eq) ? 1 : 0;
        }
        mask[(size_t)b * L_TOK + i] = sel;
    }
}

// ---------- 3) convert+transpose w_block (fp32) -> WT bf16 [n][k] ----------
__global__ __launch_bounds__(256) void transpose_kernel(const float* __restrict__ W,
                                                        u16* __restrict__ WT) {
    __shared__ u16 tile[32][33];
    int bx = blockIdx.x * 32, by = blockIdx.y * 32;
    int tx = threadIdx.x & 31, ty = threadIdx.x >> 5;  // 32 x 8
    for (int r = ty; r < 32; r += 8)
        tile[r][tx] = f2bf(W[(size_t)(by + r) * DIM + bx + tx]);
    __syncthreads();
    for (int r = ty; r < 32; r += 8)
        WT[(size_t)(bx + r) * DIM + by + tx] = tile[tx][r];
}

// ---------- 4) GEMM y = x @ W (bf16 MFMA, fp32 acc), gelu, masked scatter ----------
#define BM 128
#define BN 128
#define BK 32

__global__ __launch_bounds__(256) void gemm_kernel(const float* __restrict__ X,
                                                   const u16* __restrict__ WT,
                                                   const int* __restrict__ mask,
                                                   float* __restrict__ out) {
    __shared__ alignas(16) u16 As[BM * BK];  // [row][k] bf16 (converted in regs)
    __shared__ alignas(16) u16 Bs[BN * BK];  // [n][k]   bf16 (async from WT)
    const int tid = threadIdx.x;
    const int wave = tid >> 6, lane = tid & 63;
    const int wm = wave >> 1, wn = wave & 1;
    const size_t rowbase = (size_t)blockIdx.x * BM;
    const int colbase = blockIdx.y * BN;

    f32x4 acc[4][4] = {};

    // B staging: 512 x 16B chunks via global_load_lds
    const int cb0 = tid, cb1 = tid + 256;
    const int br0 = cb0 >> 2, bk0 = (cb0 & 3) * 8;
    const int br1 = cb1 >> 2, bk1 = (cb1 & 3) * 8;
    // A staging: thread t handles 16 contiguous fp32 of row (t>>1), half (t&1)
    const int arow = tid >> 1, ahalf = tid & 1;

    const int q = lane >> 4, mrow = lane & 15;

    for (int kt = 0; kt < DIM; kt += BK) {
        async_copy16(WT + (size_t)(colbase + br0) * DIM + kt + bk0, Bs + cb0 * 8);
        async_copy16(WT + (size_t)(colbase + br1) * DIM + kt + bk1, Bs + cb1 * 8);

        const float4* xp = (const float4*)(X + (rowbase + arow) * DIM + kt + ahalf * 16);
        float4 v0 = xp[0], v1 = xp[1], v2 = xp[2], v3 = xp[3];
        union { short8 s[2]; u32 u[8]; } pk;
        pk.u[0] = cvt2(v0.x, v0.y); pk.u[1] = cvt2(v0.z, v0.w);
        pk.u[2] = cvt2(v1.x, v1.y); pk.u[3] = cvt2(v1.z, v1.w);
        pk.u[4] = cvt2(v2.x, v2.y); pk.u[5] = cvt2(v2.z, v2.w);
        pk.u[6] = cvt2(v3.x, v3.y); pk.u[7] = cvt2(v3.z, v3.w);
        *(short8*)(As + arow * BK + ahalf * 16)     = pk.s[0];
        *(short8*)(As + arow * BK + ahalf * 16 + 8) = pk.s[1];

        __syncthreads();   // drains vmcnt (B) + lgkm (A writes)

        short8 a[4], b[4];
#pragma unroll
        for (int i = 0; i < 4; ++i)
            a[i] = *(const short8*)(As + (wm * 64 + i * 16 + mrow) * BK + q * 8);
#pragma unroll
        for (int j = 0; j < 4; ++j)
            b[j] = *(const short8*)(Bs + (wn * 64 + j * 16 + mrow) * BK + q * 8);
#pragma unroll
        for (int i = 0; i < 4; ++i)
#pragma unroll
            for (int j = 0; j < 4; ++j)
                acc[i][j] = __builtin_amdgcn_mfma_f32_16x16x32_bf16(a[i], b[j], acc[i][j], 0, 0, 0);
        __syncthreads();   // all ds_reads done before next staging overwrite
    }

    // epilogue: C/D layout col=lane&15, row=(lane>>4)*4+reg
#pragma unroll
    for (int i = 0; i < 4; ++i) {
#pragma unroll
        for (int r = 0; r < 4; ++r) {
            size_t grow = rowbase + wm * 64 + i * 16 + q * 4 + r;
            if (mask[grow]) {
#pragma unroll
                for (int j = 0; j < 4; ++j) {
                    float g = gelu_tanh(acc[i][j][r]);
                    int col = colbase + wn * 64 + j * 16 + mrow;
                    out[grow * DIM + col] = g;
                }
            }
        }
    }
}

// ---------- 5) pass-through for unselected tokens (bit-exact fp32 copy) ----------
__global__ __launch_bounds__(256) void passthrough_kernel(const float* __restrict__ x,
                                                          const int* __restrict__ mask,
                                                          float* __restrict__ out) {
    size_t c = (size_t)blockIdx.x * 256 + threadIdx.x;  // float4 chunk id
    int token = (int)(c >> 8);                          // 256 chunks per token
    if (!mask[token]) {
        ((float4*)out)[c] = ((const float4*)x)[c];
    }
}

extern "C" void kernel_launch(void* const* d_in, const int* in_sizes, int n_in,
                              void* d_out, int out_size, void* d_ws, size_t ws_size,
                              hipStream_t stream) {
    const float* x  = (const float*)d_in[0];   // [4,8192,1024] fp32
    const float* wr = (const float*)d_in[1];   // [1024] fp32
    const float* wb = (const float*)d_in[2];   // [1024,1024] fp32
    float* out = (float*)d_out;

    float* scores = (float*)d_ws;                            // 128 KB
    int*   mask   = (int*)((char*)d_ws + NTOK * 4);          // 128 KB
    u16*   WT     = (u16*)((char*)d_ws + NTOK * 8);          // 2 MB bf16

    score_kernel<<<NTOK / 4, 256, 0, stream>>>(x, wr, scores);
    select_kernel<<<BATCH, 1024, 0, stream>>>(scores, mask);
    transpose_kernel<<<dim3(DIM / 32, DIM / 32), 256, 0, stream>>>(wb, WT);
    gemm_kernel<<<dim3(NTOK / BM, DIM / BN), 256, 0, stream>>>(x, WT, mask, out);
    passthrough_kernel<<<(NTOK * 256) / 256, 256, 0, stream>>>(x, mask, out);
}

// Round 4
// 380.630 us; speedup vs baseline: 1.7637x; 1.7270x over previous
//
#include <hip/hip_runtime.h>
#include <hip/hip_bf16.h>

typedef unsigned short u16;
typedef unsigned int u32;
typedef __attribute__((ext_vector_type(8))) short short8;   // 8 x bf16 (4 VGPRs)
typedef __attribute__((ext_vector_type(4))) float f32x4;

#define L_TOK 8192
#define BATCH 4
#define DIM 1024
#define KSEL 6144
#define NTOK (BATCH * L_TOK)   // 32768

// ---------- helpers ----------
__device__ __forceinline__ u16 f2bf(float f) {  // RNE fp32 -> bf16
    u32 u = __float_as_uint(f);
    return (u16)((u + 0x7fffu + ((u >> 16) & 1u)) >> 16);
}
__device__ __forceinline__ u32 cvt2(float a, float b) {  // pack 2 bf16 (RNE)
    __hip_bfloat162 h = __float22bfloat162_rn(float2{a, b});
    u32 r;
    __builtin_memcpy(&r, &h, 4);
    return r;
}
__device__ __forceinline__ float gelu_tanh(float v) {
    float inner = 0.7978845608028654f * (v + 0.044715f * v * v * v);
    return 0.5f * v * (1.0f + tanhf(inner));
}
__device__ __forceinline__ void async_copy16(const void* g, void* l) {
    __builtin_amdgcn_global_load_lds(
        (const __attribute__((address_space(1))) void*)g,
        (__attribute__((address_space(3))) void*)l, 16, 0, 0);
}

// ---------- 1) router scores: scores[t] = sum_d x[t][d] * w_router[d] (fp64 acc) ----------
__global__ __launch_bounds__(256) void score_kernel(const float* __restrict__ x,
                                                    const float* __restrict__ wr,
                                                    float* __restrict__ scores) {
    int token = blockIdx.x * 4 + (threadIdx.x >> 6);
    int lane = threadIdx.x & 63;
    const float4* xr = (const float4*)(x + (size_t)token * DIM) + lane * 4;
    const float4* wp = (const float4*)wr + lane * 4;
    double acc = 0.0;
#pragma unroll
    for (int c = 0; c < 4; ++c) {
        float4 xv = xr[c];
        float4 wv = wp[c];
        acc += (double)xv.x * wv.x + (double)xv.y * wv.y +
               (double)xv.z * wv.z + (double)xv.w * wv.w;
    }
#pragma unroll
    for (int off = 32; off > 0; off >>= 1) acc += __shfl_down(acc, off, 64);
    if (lane == 0) scores[token] = (float)acc;
}

// ---------- 2) per-row top-k: 4-pass radix select + PARALLEL stable tie-rank ----------
__global__ __launch_bounds__(1024) void select_kernel(const float* __restrict__ scores,
                                                      int* __restrict__ mask) {
    __shared__ u32 keys[L_TOK];      // 32 KB
    __shared__ int hist[256];
    __shared__ int g0[256], g1[256];
    __shared__ int wsum[16];
    __shared__ int sel_digit, greater_cnt;
    const int b = blockIdx.x;
    const int tid = threadIdx.x;
    const int lane = tid & 63, wid = tid >> 6;
    const float* s = scores + (size_t)b * L_TOK;
    for (int i = tid; i < L_TOK; i += 1024) {
        u32 u = __float_as_uint(s[i]);
        keys[i] = (u & 0x80000000u) ? ~u : (u | 0x80000000u);  // order-preserving map
    }

    u32 prefix = 0;
    int need = KSEL;
#pragma unroll
    for (int pass = 0; pass < 4; ++pass) {
        const int shift = 24 - 8 * pass;
        const u32 pmask = (pass == 0) ? 0u : (0xFFFFFFFFu << (shift + 8));
        if (tid < 256) hist[tid] = 0;
        __syncthreads();   // hist zeroed; also covers keys[] visibility
        for (int i = tid; i < L_TOK; i += 1024) {
            u32 key = keys[i];
            if ((key & pmask) == prefix)
                atomicAdd(&hist[(key >> shift) & 0xffu], 1);
        }
        __syncthreads();
        // suffix-inclusive scan: G[d] = #active with digit >= d
        if (tid < 256) g0[tid] = hist[tid];
        __syncthreads();
        int* src = g0;
        int* dst = g1;
        for (int step = 1; step < 256; step <<= 1) {
            if (tid < 256) {
                int v = src[tid];
                if (tid + step < 256) v += src[tid + step];
                dst[tid] = v;
            }
            __syncthreads();
            int* t = src; src = dst; dst = t;
        }
        // d* = max{d : G[d] >= need}; # strictly greater = G[d*+1]
        if (tid < 256) {
            int Gd = src[tid];
            int Gn = (tid == 255) ? 0 : src[tid + 1];
            if (Gd >= need && Gn < need) { sel_digit = tid; greater_cnt = Gn; }
        }
        __syncthreads();
        prefix |= ((u32)sel_digit) << shift;
        need -= greater_cnt;
        __syncthreads();
    }
    const u32 T = prefix;        // exact k-th largest key
    const int need_eq = need;    // # of ==T tokens to take (lowest index first)

    // parallel stable rank: thread t owns contiguous chunk [8t, 8t+8)
    const int base = tid * 8;
    u32 kv[8];
    int eq = 0;
#pragma unroll
    for (int c = 0; c < 8; ++c) { kv[c] = keys[base + c]; eq += (kv[c] == T); }
    int inc = eq;   // wave-level inclusive scan of eq counts
#pragma unroll
    for (int off = 1; off < 64; off <<= 1) {
        int n = __shfl_up(inc, off, 64);
        if (lane >= off) inc += n;
    }
    if (lane == 63) wsum[wid] = inc;
    __syncthreads();
    int wbase = 0;
    for (int w = 0; w < wid; ++w) wbase += wsum[w];  // <=15 broadcast LDS reads
    int rank = wbase + inc - eq;   // exclusive rank at chunk start
    int sel[8];
#pragma unroll
    for (int c = 0; c < 8; ++c) {
        u32 key = kv[c];
        int se = 0;
        if (key > T) se = 1;
        else if (key == T) { se = (rank < need_eq) ? 1 : 0; rank++; }
        sel[c] = se;
    }
    int4* mp = (int4*)(mask + (size_t)b * L_TOK + base);
    mp[0] = int4{sel[0], sel[1], sel[2], sel[3]};
    mp[1] = int4{sel[4], sel[5], sel[6], sel[7]};
}

// ---------- 3a) convert+transpose w_block (fp32) -> WT bf16 [n][k] ----------
__global__ __launch_bounds__(256) void transpose_kernel(const float* __restrict__ W,
                                                        u16* __restrict__ WT) {
    __shared__ u16 tile[32][33];
    int bx = blockIdx.x * 32, by = blockIdx.y * 32;
    int tx = threadIdx.x & 31, ty = threadIdx.x >> 5;  // 32 x 8
    for (int r = ty; r < 32; r += 8)
        tile[r][tx] = f2bf(W[(size_t)(by + r) * DIM + bx + tx]);
    __syncthreads();
    for (int r = ty; r < 32; r += 8)
        WT[(size_t)(bx + r) * DIM + by + tx] = tile[tx][r];
}

// ---------- 3b) convert X (fp32) -> Xb (bf16), identical RNE to in-loop cvt ----------
__global__ __launch_bounds__(256) void cvt_kernel(const float* __restrict__ x,
                                                  u16* __restrict__ xb) {
    size_t i = ((size_t)blockIdx.x * 256 + threadIdx.x) * 8;
    float4 v0 = *(const float4*)(x + i);
    float4 v1 = *(const float4*)(x + i + 4);
    union { short8 s; u32 u[4]; } pk;
    pk.u[0] = cvt2(v0.x, v0.y); pk.u[1] = cvt2(v0.z, v0.w);
    pk.u[2] = cvt2(v1.x, v1.y); pk.u[3] = cvt2(v1.z, v1.w);
    *(short8*)(xb + i) = pk.s;
}

#define BM 128
#define BN 128
#define BK 32

// ---------- 4) GEMM y = Xb @ W (pure bf16, m97 structure), gelu, masked scatter ----------
__global__ __launch_bounds__(256) void gemm_bf16_kernel(const u16* __restrict__ Xb,
                                                        const u16* __restrict__ WT,
                                                        const int* __restrict__ mask,
                                                        float* __restrict__ out) {
    __shared__ alignas(16) u16 As[BM * BK];  // [row][k] bf16
    __shared__ alignas(16) u16 Bs[BN * BK];  // [n][k]   bf16
    const int tid = threadIdx.x;
    const int wave = tid >> 6, lane = tid & 63;
    const int wm = wave >> 1, wn = wave & 1;
    const size_t rowbase = (size_t)blockIdx.x * BM;
    const int colbase = blockIdx.y * BN;

    f32x4 acc[4][4] = {};

    const int ca0 = tid, ca1 = tid + 256;          // 16B chunk ids (512 per tile)
    const int r0 = ca0 >> 2, k0 = (ca0 & 3) * 8;
    const int r1 = ca1 >> 2, k1 = (ca1 & 3) * 8;
    const int q = lane >> 4, mrow = lane & 15;

    for (int kt = 0; kt < DIM; kt += BK) {
        async_copy16(Xb + (rowbase + r0) * DIM + kt + k0, As + ca0 * 8);
        async_copy16(Xb + (rowbase + r1) * DIM + kt + k1, As + ca1 * 8);
        async_copy16(WT + (size_t)(colbase + r0) * DIM + kt + k0, Bs + ca0 * 8);
        async_copy16(WT + (size_t)(colbase + r1) * DIM + kt + k1, Bs + ca1 * 8);
        __syncthreads();   // drains vmcnt before barrier -> tiles visible

        short8 a[4], b[4];
#pragma unroll
        for (int i = 0; i < 4; ++i)
            a[i] = *(const short8*)(As + (wm * 64 + i * 16 + mrow) * BK + q * 8);
#pragma unroll
        for (int j = 0; j < 4; ++j)
            b[j] = *(const short8*)(Bs + (wn * 64 + j * 16 + mrow) * BK + q * 8);
#pragma unroll
        for (int i = 0; i < 4; ++i)
#pragma unroll
            for (int j = 0; j < 4; ++j)
                acc[i][j] = __builtin_amdgcn_mfma_f32_16x16x32_bf16(a[i], b[j], acc[i][j], 0, 0, 0);
        __syncthreads();
    }

#pragma unroll
    for (int i = 0; i < 4; ++i) {
#pragma unroll
        for (int r = 0; r < 4; ++r) {
            size_t grow = rowbase + wm * 64 + i * 16 + q * 4 + r;
            if (mask[grow]) {
#pragma unroll
                for (int j = 0; j < 4; ++j) {
                    float g = gelu_tanh(acc[i][j][r]);
                    int col = colbase + wn * 64 + j * 16 + mrow;
                    out[grow * DIM + col] = g;
                }
            }
        }
    }
}

// ---------- 4-fallback) GEMM with in-loop fp32->bf16 A conversion (small ws) ----------
__global__ __launch_bounds__(256) void gemm_f32_kernel(const float* __restrict__ X,
                                                       const u16* __restrict__ WT,
                                                       const int* __restrict__ mask,
                                                       float* __restrict__ out) {
    __shared__ alignas(16) u16 As[BM * BK];
    __shared__ alignas(16) u16 Bs[BN * BK];
    const int tid = threadIdx.x;
    const int wave = tid >> 6, lane = tid & 63;
    const int wm = wave >> 1, wn = wave & 1;
    const size_t rowbase = (size_t)blockIdx.x * BM;
    const int colbase = blockIdx.y * BN;

    f32x4 acc[4][4] = {};

    const int cb0 = tid, cb1 = tid + 256;
    const int br0 = cb0 >> 2, bk0 = (cb0 & 3) * 8;
    const int br1 = cb1 >> 2, bk1 = (cb1 & 3) * 8;
    const int arow = tid >> 1, ahalf = tid & 1;
    const int q = lane >> 4, mrow = lane & 15;

    for (int kt = 0; kt < DIM; kt += BK) {
        async_copy16(WT + (size_t)(colbase + br0) * DIM + kt + bk0, Bs + cb0 * 8);
        async_copy16(WT + (size_t)(colbase + br1) * DIM + kt + bk1, Bs + cb1 * 8);

        const float4* xp = (const float4*)(X + (rowbase + arow) * DIM + kt + ahalf * 16);
        float4 v0 = xp[0], v1 = xp[1], v2 = xp[2], v3 = xp[3];
        union { short8 s[2]; u32 u[8]; } pk;
        pk.u[0] = cvt2(v0.x, v0.y); pk.u[1] = cvt2(v0.z, v0.w);
        pk.u[2] = cvt2(v1.x, v1.y); pk.u[3] = cvt2(v1.z, v1.w);
        pk.u[4] = cvt2(v2.x, v2.y); pk.u[5] = cvt2(v2.z, v2.w);
        pk.u[6] = cvt2(v3.x, v3.y); pk.u[7] = cvt2(v3.z, v3.w);
        *(short8*)(As + arow * BK + ahalf * 16)     = pk.s[0];
        *(short8*)(As + arow * BK + ahalf * 16 + 8) = pk.s[1];

        __syncthreads();

        short8 a[4], b[4];
#pragma unroll
        for (int i = 0; i < 4; ++i)
            a[i] = *(const short8*)(As + (wm * 64 + i * 16 + mrow) * BK + q * 8);
#pragma unroll
        for (int j = 0; j < 4; ++j)
            b[j] = *(const short8*)(Bs + (wn * 64 + j * 16 + mrow) * BK + q * 8);
#pragma unroll
        for (int i = 0; i < 4; ++i)
#pragma unroll
            for (int j = 0; j < 4; ++j)
                acc[i][j] = __builtin_amdgcn_mfma_f32_16x16x32_bf16(a[i], b[j], acc[i][j], 0, 0, 0);
        __syncthreads();
    }

#pragma unroll
    for (int i = 0; i < 4; ++i) {
#pragma unroll
        for (int r = 0; r < 4; ++r) {
            size_t grow = rowbase + wm * 64 + i * 16 + q * 4 + r;
            if (mask[grow]) {
#pragma unroll
                for (int j = 0; j < 4; ++j) {
                    float g = gelu_tanh(acc[i][j][r]);
                    int col = colbase + wn * 64 + j * 16 + mrow;
                    out[grow * DIM + col] = g;
                }
            }
        }
    }
}

// ---------- 5) pass-through for unselected tokens (bit-exact fp32 copy) ----------
__global__ __launch_bounds__(256) void passthrough_kernel(const float* __restrict__ x,
                                                          const int* __restrict__ mask,
                                                          float* __restrict__ out) {
    size_t c = (size_t)blockIdx.x * 256 + threadIdx.x;  // float4 chunk id
    int token = (int)(c >> 8);                          // 256 chunks per token
    if (!mask[token]) {
        ((float4*)out)[c] = ((const float4*)x)[c];
    }
}

extern "C" void kernel_launch(void* const* d_in, const int* in_sizes, int n_in,
                              void* d_out, int out_size, void* d_ws, size_t ws_size,
                              hipStream_t stream) {
    const float* x  = (const float*)d_in[0];   // [4,8192,1024] fp32
    const float* wr = (const float*)d_in[1];   // [1024] fp32
    const float* wb = (const float*)d_in[2];   // [1024,1024] fp32
    float* out = (float*)d_out;

    float* scores = (float*)d_ws;                            // 128 KB
    int*   mask   = (int*)((char*)d_ws + NTOK * 4);          // 128 KB
    u16*   WT     = (u16*)((char*)d_ws + NTOK * 8);          // 2 MB bf16
    u16*   Xb     = (u16*)((char*)d_ws + NTOK * 8 + DIM * DIM * 2);  // 64 MB bf16

    const size_t need_ws = (size_t)NTOK * 8 + (size_t)DIM * DIM * 2
                         + (size_t)NTOK * DIM * 2;

    score_kernel<<<NTOK / 4, 256, 0, stream>>>(x, wr, scores);
    select_kernel<<<BATCH, 1024, 0, stream>>>(scores, mask);
    transpose_kernel<<<dim3(DIM / 32, DIM / 32), 256, 0, stream>>>(wb, WT);
    if (ws_size >= need_ws) {
        cvt_kernel<<<(NTOK * (DIM / 8)) / 256, 256, 0, stream>>>(x, Xb);
        gemm_bf16_kernel<<<dim3(NTOK / BM, DIM / BN), 256, 0, stream>>>(Xb, WT, mask, out);
    } else {
        gemm_f32_kernel<<<dim3(NTOK / BM, DIM / BN), 256, 0, stream>>>(x, WT, mask, out);
    }
    passthrough_kernel<<<(NTOK * 256) / 256, 256, 0, stream>>>(x, mask, out);
}